// Round 10
// baseline (385.703 us; speedup 1.0000x reference)
//
#include <hip/hip_runtime.h>

#define HEADS 8
#define HDIM 32
#define NTOK 1024
#define CDIM 256
#define BATCH 16
#define ATT_SCALE 0.17677669529663687f  // 32^-0.5
#define L2E 1.4426950408889634f
#define XROW 66     // qkv LDS x-tile row stride (f32): even (8B align), 66%32=2
#define BSTRQ 1288  // attn bias copy stride (floats): 16B-aligned, 1288%32=8

typedef __attribute__((ext_vector_type(8))) short bf16x8;   // 8 bf16, 4 VGPRs
typedef __attribute__((ext_vector_type(4))) float f32x4;    // MFMA C/D

__device__ __forceinline__ unsigned short f2bf(float f) {
    unsigned int u = __float_as_uint(f);
    return (unsigned short)((u + 0x7fffu + ((u >> 16) & 1u)) >> 16);  // RNE
}

// pack two f32 -> (bf16(lo) | bf16(hi)<<16) in one instruction; RNE == f2bf
__device__ __forceinline__ unsigned cvt_pk_bf16(float lo, float hi) {
    unsigned r;
    asm("v_cvt_pk_bf16_f32 %0, %1, %2" : "=v"(r) : "v"(lo), "v"(hi));
    return r;
}

// ---------------------------------------------------------------------------
// Weight prep: fp32 -> bf16, Wk pre-scaled by ATT_SCALE*log2(e).
// ---------------------------------------------------------------------------
__global__ __launch_bounds__(256) void prepw_kernel(
    const float* __restrict__ Wq, const float* __restrict__ Wk,
    const float* __restrict__ Wv, const float* __restrict__ Wo,
    unsigned short* __restrict__ w16)
{
    const int t = threadIdx.x;
    const int which = blockIdx.y;
    const float* src = (which == 0) ? Wq : ((which == 1) ? Wk : ((which == 2) ? Wv : Wo));
    const float scale = (which == 1) ? (ATT_SCALE * L2E) : 1.0f;
    const int base = (blockIdx.x * 256 + t) * 16;
    #pragma unroll
    for (int i = 0; i < 4; ++i) {
        const int idx = base + i * 4;
        float4 v = *(const float4*)&src[idx];
        union { unsigned short h[4]; uint2 u; } pk;
        pk.h[0] = f2bf(v.x * scale); pk.h[1] = f2bf(v.y * scale);
        pk.h[2] = f2bf(v.z * scale); pk.h[3] = f2bf(v.w * scale);
        *(uint2*)&w16[(size_t)which * 65536 + idx] = pk.u;
    }
}

// ---------------------------------------------------------------------------
// QKV GEMM, x-deduplicated, coalesced stores (unchanged from R9).
// ---------------------------------------------------------------------------
__global__ __launch_bounds__(1024, 4) void qkv_kernel(
    const float* __restrict__ x,              // (b,c,n) f32
    const unsigned short* __restrict__ w16,   // wq|wk|wv|wo (wk pre-scaled)
    unsigned short* __restrict__ q16,         // (b,n,h,32)
    unsigned short* __restrict__ k16,         // (b,h, 64 frag, 512)
    unsigned short* __restrict__ v16)         // (b,h, 64 frag, 512)
{
    __shared__ __align__(16) unsigned char smem[65536];     // lx overlay + A/B
    float (*lx)[32 * XROW] = (float(*)[32 * XROW])smem;     // 2 x 8.25 KB ping-pong
    unsigned short* bufA = (unsigned short*)smem;           // 32 KB (epilogue)
    unsigned short* bufB = (unsigned short*)(smem + 32768); // 32 KB (epilogue)

    const int id  = blockIdx.x;               // 0..255
    const int b   = (id & 7) * 2 + (id >> 7); // id%8 == b>>1 == attn's XCD for b
    const int t16 = (id >> 3) & 15;

    const int t = threadIdx.x, wid = t >> 6, lane = t & 63;
    const int g = lane >> 4, ln = lane & 15;
    const int h = wid & 7, tgrp = wid >> 3;
    const int tok0 = t16 * 64;                // block's 64 tokens
    const int trl  = tgrp * 32;               // wave's 32 tokens (block-local)
    const int tr   = tok0 + trl;              // global (== 0 mod 32)

    const float* xb = x + (size_t)b * CDIM * NTOK;
    const unsigned short* wqh = w16 + (size_t)(h * 32) * CDIM;
    const unsigned short* wkh = w16 + 65536 + (size_t)(h * 32) * CDIM;
    const unsigned short* wvh = w16 + 2 * 65536 + (size_t)(h * 32) * CDIM;

    // staging map: 1024 thr = 32 c-rows x 32 float2 (64 tokens)
    const int scc = t >> 5, sl2 = (t & 31) * 2;

    f32x4 aq[2][2], ak[2][2], av[2][2];
    #pragma unroll
    for (int m = 0; m < 2; ++m)
        #pragma unroll
        for (int n = 0; n < 2; ++n) {
            aq[m][n] = (f32x4){0.f, 0.f, 0.f, 0.f};
            ak[m][n] = (f32x4){0.f, 0.f, 0.f, 0.f};
            av[n][m] = (f32x4){0.f, 0.f, 0.f, 0.f};
        }

    // prologue: stage chunk 0
    {
        const float2 v = *(const float2*)&xb[(size_t)scc * NTOK + tok0 + sl2];
        *(float2*)&lx[0][scc * XROW + sl2] = v;
    }
    __syncthreads();

    #pragma unroll
    for (int ci = 0; ci < 8; ++ci) {
        const int cur = ci & 1;
        const int kt = ci * 32;
        if (ci < 7) {
            const float2 v = *(const float2*)&xb[(size_t)(kt + 32 + scc) * NTOK + tok0 + sl2];
            *(float2*)&lx[cur ^ 1][scc * XROW + sl2] = v;
        }
        bf16x8 xf[2];
        #pragma unroll
        for (int m = 0; m < 2; ++m) {
            const float* col = &lx[cur][(size_t)(g * 8) * XROW + trl + m * 16 + ln];
            union { unsigned u4[4]; bf16x8 v; } pk;
            #pragma unroll
            for (int p = 0; p < 4; ++p)
                pk.u4[p] = cvt_pk_bf16(col[(2 * p) * XROW], col[(2 * p + 1) * XROW]);
            xf[m] = pk.v;
        }
        bf16x8 wqf[2], wkf[2], wvf[2];
        #pragma unroll
        for (int n = 0; n < 2; ++n) {
            wqf[n] = *(const bf16x8*)&wqh[(size_t)(n * 16 + ln) * CDIM + kt + g * 8];
            wkf[n] = *(const bf16x8*)&wkh[(size_t)(n * 16 + ln) * CDIM + kt + g * 8];
            wvf[n] = *(const bf16x8*)&wvh[(size_t)(n * 16 + ln) * CDIM + kt + g * 8];
        }
        #pragma unroll
        for (int m = 0; m < 2; ++m)
            #pragma unroll
            for (int n = 0; n < 2; ++n) {
                aq[m][n] = __builtin_amdgcn_mfma_f32_16x16x32_bf16(xf[m], wqf[n], aq[m][n], 0, 0, 0);
                ak[m][n] = __builtin_amdgcn_mfma_f32_16x16x32_bf16(xf[m], wkf[n], ak[m][n], 0, 0, 0);
                av[n][m] = __builtin_amdgcn_mfma_f32_16x16x32_bf16(wvf[n], xf[m], av[n][m], 0, 0, 0);
            }
        __syncthreads();
    }

    // Phase 1: assemble K in bufA.
    #pragma unroll
    for (int m = 0; m < 2; ++m)
        #pragma unroll
        for (int n = 0; n < 2; ++n) {
            const int lhi = (2 * n + (ln >> 3)) * 16 + (m * 2 + (g >> 1)) * 4;
            unsigned short* dst = &bufA[(h * 4 + tgrp * 2 + (g & 1)) * 512 + (ln & 7)];
            #pragma unroll
            for (int r = 0; r < 4; ++r)
                dst[(lhi + r) * 8] = f2bf(ak[m][n][r]);
        }
    __syncthreads();

    // Phase 2: copy K out (dense uint4) || assemble V in bufB.
    #pragma unroll
    for (int uu = 0; uu < 2; ++uu) {
        const int u = t + uu * 1024;
        const int hu = u >> 8, off = u & 255;
        uint4 vv = *(const uint4*)&bufA[hu * 2048 + off * 8];
        *(uint4*)&k16[(size_t)(b * 8 + hu) * 32768 + t16 * 2048 + off * 8] = vv;
    }
    #pragma unroll
    for (int n = 0; n < 2; ++n) {
        const int fl = tgrp * 2 + n;
        #pragma unroll
        for (int m = 0; m < 2; ++m) {
            const int lnb = (m * 2 + (ln >> 3)) * 16 + g * 4;
            unsigned short* dst = &bufB[(h * 4 + fl) * 512 + (ln & 7)];
            #pragma unroll
            for (int r = 0; r < 4; ++r)
                dst[(lnb + r) * 8] = f2bf(av[n][m][r]);
        }
    }
    __syncthreads();

    // Phase 3: copy V out || assemble Q in bufA.
    #pragma unroll
    for (int uu = 0; uu < 2; ++uu) {
        const int u = t + uu * 1024;
        const int hu = u >> 8, off = u & 255;
        uint4 vv = *(const uint4*)&bufB[hu * 2048 + off * 8];
        *(uint4*)&v16[(size_t)(b * 8 + hu) * 32768 + t16 * 2048 + off * 8] = vv;
    }
    #pragma unroll
    for (int m = 0; m < 2; ++m)
        #pragma unroll
        for (int n = 0; n < 2; ++n)
            #pragma unroll
            for (int r = 0; r < 4; ++r)
                bufA[(trl + m * 16 + g * 4 + r) * 256 + h * 32 + n * 16 + ln] = f2bf(aq[m][n][r]);
    __syncthreads();

    // Phase 4: copy Q out.
    #pragma unroll
    for (int uu = 0; uu < 2; ++uu) {
        const int u = t + uu * 1024;
        *(uint4*)&q16[((size_t)(b * NTOK + tok0)) * 256 + u * 8] = *(const uint4*)&bufA[u * 8];
    }
}

// ---------------------------------------------------------------------------
// Flash attention, KEY-SPLIT for occupancy.  Block = (b, h, query-quarter):
// 512 blocks x 1024 thr = 524288 threads = 2048/CU -> 2 blocks/CU, 8 waves/
// SIMD (2x the old 1-block/152KB-LDS version).  16 waves = 8 q-groups x 2
// key-halves; waves kh=0/1 each run 512 keys of the same 32 queries.  K/V
// are read straight from L2 (global, coalesced 1KB segments, same-XCD
// producer) -- no K/V LDS.  LDS = bias table (20.6 KB) overlaid after the
// loop by the partial-combine buffer (48 KB) + otr (20 KB) = 69.6 KB -> 2
// blocks/CU.  Softmax uses plain exp2 (no running max), so key-half partials
// combine exactly: o = oA+oB, ls = lsA+lsB, out = o/ls.
// ---------------------------------------------------------------------------
__global__ __launch_bounds__(1024, 8) void attn_kernel(
    const unsigned short* __restrict__ q16,   // (b,n,h,32)
    const unsigned short* __restrict__ k16,   // (b,h,64,512) frag-major
    const unsigned short* __restrict__ v16,   // (b,h,64,512) frag-major
    const float* __restrict__ rel_bias,       // (h, 3969)
    unsigned short* __restrict__ ao16)        // (b, n, 256)
{
    __shared__ __align__(16) unsigned char smem[49152 + 20480];
    float* bias4 = (float*)smem;              // [4][BSTRQ] = 20.6 KB (loop phase)
    float* part  = (float*)smem;              // [8][64][24] = 48 KB (combine phase)
    unsigned short (*otr)[32][40] = (unsigned short(*)[32][40])(smem + 49152);

    const int id = blockIdx.x;                // 0..511
    const int b  = (id & 7) * 2 + ((id >> 3) & 1);   // id%8 == b>>1 (XCD-local k/v)
    const int h  = (id >> 4) & 7;
    const int quarter = id >> 7;

    const int t = threadIdx.x, wid = t >> 6, lane = t & 63;
    const int g = lane >> 4, ln = lane & 15;
    const int qg = wid & 7, kh = wid >> 3;
    const int q0 = quarter * 256 + qg * 32;   // wave's 32 queries

    const unsigned short* kbh = k16 + (size_t)(b * 8 + h) * 32768;
    const unsigned short* vbh = v16 + (size_t)(b * 8 + h) * 32768;

    // ---- Q fragments ----
    const bf16x8 aq0 = *(const bf16x8*)&q16[((size_t)(b * NTOK + q0 + ln) * 8 + h) * 32 + g * 8];
    const bf16x8 aq1 = *(const bf16x8*)&q16[((size_t)(b * NTOK + q0 + 16 + ln) * 8 + h) * 32 + g * 8];

    // ---- bias*log2e table: 4 shift-aligned copies, window for this quarter ----
    // global bias idx for (q,k) = k - q + 1056; table i maps to brow[S0 + a + i].
    {
        const int S0 = 801 - 256 * quarter;   // >= 33 for quarter=3
        const float* brow = rel_bias + (size_t)h * 3969;
        for (int i = t; i < 1279; i += 1024) {
            #pragma unroll
            for (int a = 0; a < 4; ++a)
                bias4[a * BSTRQ + i] = brow[S0 + a + i] * L2E;
        }
    }
    __syncthreads();

    // local bias offset: offL = 1056 + 8g - q - S0 = 255 + 8g - qg*32 - ln  (in [16,279])
    const int offL = 255 + 8 * g - qg * 32 - ln;
    const int ba = offL & 3;
    const float* bb = &bias4[ba * BSTRQ + (offL - ba)];

    f32x4 o00 = {0.f,0.f,0.f,0.f}, o01 = {0.f,0.f,0.f,0.f};
    f32x4 o10 = {0.f,0.f,0.f,0.f}, o11 = {0.f,0.f,0.f,0.f};
    f32x4 ls0 = {0.f,0.f,0.f,0.f}, ls1 = {0.f,0.f,0.f,0.f};
    const short one_bf = (short)0x3F80;
    const bf16x8 ones = {one_bf,one_bf,one_bf,one_bf,one_bf,one_bf,one_bf,one_bf};

    const int kk0 = kh * 512;                 // wave's key-half base (absolute)
    const int fb  = kh * 32;                  // frag base

    // prologue: iter-0 K fragments (global/L2) + bias C-operands (LDS)
    bf16x8 kf0 = *(const bf16x8*)&kbh[(size_t)fb * 512 + lane * 8];
    bf16x8 kf1 = *(const bf16x8*)&kbh[(size_t)(fb + 1) * 512 + lane * 8];
    f32x4  cA0 = *(const f32x4*)&bb[kk0];
    f32x4  cA1 = *(const f32x4*)&bb[kk0 + 4];
    f32x4  cB0 = *(const f32x4*)&bb[kk0 - 16];
    f32x4  cB1 = *(const f32x4*)&bb[kk0 - 12];

    for (int kbl = 0; kbl < 512; kbl += 32) {
        const int fi = fb + (kbl >> 5) * 2;
        // V for THIS iter (global/L2): consumed after S-MFMA + exp -> slack.
        const bf16x8 vA0 = *(const bf16x8*)&vbh[(size_t)fi * 512 + lane * 8];
        const bf16x8 vA1 = *(const bf16x8*)&vbh[(size_t)(fi + 1) * 512 + lane * 8];
        // prefetch NEXT iter's K + bias (wrap within the half; last is dead).
        const int knl = (kbl + 32) & 511;
        const int kn  = kk0 + knl;
        const int fn  = fb + (knl >> 5) * 2;
        const bf16x8 nk0 = *(const bf16x8*)&kbh[(size_t)fn * 512 + lane * 8];
        const bf16x8 nk1 = *(const bf16x8*)&kbh[(size_t)(fn + 1) * 512 + lane * 8];
        const f32x4  nA0 = *(const f32x4*)&bb[kn];
        const f32x4  nA1 = *(const f32x4*)&bb[kn + 4];
        const f32x4  nB0 = *(const f32x4*)&bb[kn - 16];
        const f32x4  nB1 = *(const f32x4*)&bb[kn - 12];

        __builtin_amdgcn_s_setprio(1);
        f32x4 s00 = __builtin_amdgcn_mfma_f32_16x16x32_bf16(kf0, aq0, cA0, 0, 0, 0);
        f32x4 s01 = __builtin_amdgcn_mfma_f32_16x16x32_bf16(kf1, aq0, cA1, 0, 0, 0);
        f32x4 s10 = __builtin_amdgcn_mfma_f32_16x16x32_bf16(kf0, aq1, cB0, 0, 0, 0);
        f32x4 s11 = __builtin_amdgcn_mfma_f32_16x16x32_bf16(kf1, aq1, cB1, 0, 0, 0);
        __builtin_amdgcn_s_setprio(0);

        union { unsigned u4[4]; bf16x8 v; } ap0, ap1;
        ap0.u4[0] = cvt_pk_bf16(__builtin_amdgcn_exp2f(s00[0]), __builtin_amdgcn_exp2f(s00[1]));
        ap0.u4[1] = cvt_pk_bf16(__builtin_amdgcn_exp2f(s00[2]), __builtin_amdgcn_exp2f(s00[3]));
        ap0.u4[2] = cvt_pk_bf16(__builtin_amdgcn_exp2f(s01[0]), __builtin_amdgcn_exp2f(s01[1]));
        ap0.u4[3] = cvt_pk_bf16(__builtin_amdgcn_exp2f(s01[2]), __builtin_amdgcn_exp2f(s01[3]));
        ap1.u4[0] = cvt_pk_bf16(__builtin_amdgcn_exp2f(s10[0]), __builtin_amdgcn_exp2f(s10[1]));
        ap1.u4[1] = cvt_pk_bf16(__builtin_amdgcn_exp2f(s10[2]), __builtin_amdgcn_exp2f(s10[3]));
        ap1.u4[2] = cvt_pk_bf16(__builtin_amdgcn_exp2f(s11[0]), __builtin_amdgcn_exp2f(s11[1]));
        ap1.u4[3] = cvt_pk_bf16(__builtin_amdgcn_exp2f(s11[2]), __builtin_amdgcn_exp2f(s11[3]));

        __builtin_amdgcn_s_setprio(1);
        o00 = __builtin_amdgcn_mfma_f32_16x16x32_bf16(ap0.v, vA0, o00, 0, 0, 0);
        o01 = __builtin_amdgcn_mfma_f32_16x16x32_bf16(ap0.v, vA1, o01, 0, 0, 0);
        ls0 = __builtin_amdgcn_mfma_f32_16x16x32_bf16(ap0.v, ones, ls0, 0, 0, 0);
        o10 = __builtin_amdgcn_mfma_f32_16x16x32_bf16(ap1.v, vA0, o10, 0, 0, 0);
        o11 = __builtin_amdgcn_mfma_f32_16x16x32_bf16(ap1.v, vA1, o11, 0, 0, 0);
        ls1 = __builtin_amdgcn_mfma_f32_16x16x32_bf16(ap1.v, ones, ls1, 0, 0, 0);
        __builtin_amdgcn_s_setprio(0);

        kf0 = nk0; kf1 = nk1;
        cA0 = nA0; cA1 = nA1; cB0 = nB0; cB1 = nB1;
    }

    __syncthreads();   // all waves past bias reads; overlay part on bias region

    // ---- key-half combine: kh=1 writes partials, kh=0 merges ----
    if (kh == 1) {
        float* p = &part[((size_t)qg * 64 + lane) * 24];
        *(f32x4*)&p[0]  = o00;  *(f32x4*)&p[4]  = o01;
        *(f32x4*)&p[8]  = o10;  *(f32x4*)&p[12] = o11;
        *(f32x4*)&p[16] = ls0;  *(f32x4*)&p[20] = ls1;
    }
    __syncthreads();

    if (kh == 0) {
        const float* p = &part[((size_t)qg * 64 + lane) * 24];
        const f32x4 p00 = *(const f32x4*)&p[0],  p01 = *(const f32x4*)&p[4];
        const f32x4 p10 = *(const f32x4*)&p[8],  p11 = *(const f32x4*)&p[12];
        const f32x4 pl0 = *(const f32x4*)&p[16], pl1 = *(const f32x4*)&p[20];
        #pragma unroll
        for (int r = 0; r < 4; ++r) {
            const float l0 = ls0[r] + pl0[r], l1 = ls1[r] + pl1[r];
            const float i0 = 1.f / l0, i1 = 1.f / l1;
            o00[r] = (o00[r] + p00[r]) * i0;
            o01[r] = (o01[r] + p01[r]) * i0;
            o10[r] = (o10[r] + p10[r]) * i1;
            o11[r] = (o11[r] + p11[r]) * i1;
        }
        #pragma unroll
        for (int r = 0; r < 4; ++r) {
            otr[qg][g * 4 + r][ln]           = f2bf(o00[r]);
            otr[qg][g * 4 + r][16 + ln]      = f2bf(o01[r]);
            otr[qg][16 + g * 4 + r][ln]      = f2bf(o10[r]);
            otr[qg][16 + g * 4 + r][16 + ln] = f2bf(o11[r]);
        }
        // same-wave region: DS in-order, no barrier.  2 lanes/row x 16 d each.
        const int row = lane >> 1;
        const int ch  = (lane & 1) * 16;
        uint4 st0 = *(uint4*)&otr[qg][row][ch];
        uint4 st1 = *(uint4*)&otr[qg][row][ch + 8];
        unsigned short* dst = &ao16[((size_t)b * NTOK + q0 + row) * CDIM + h * HDIM + ch];
        *(uint4*)dst     = st0;
        *(uint4*)&dst[8] = st1;
    }
}

// ---------------------------------------------------------------------------
// Output projection: 64c x 128p per block, wave = 2 c-frags x 4 p-frags.
// XCD-swizzled flat grid 512.  (Unchanged.)
// ---------------------------------------------------------------------------
__global__ __launch_bounds__(256) void outproj_kernel(
    const unsigned short* __restrict__ ao16,  // (b,n,256)
    const unsigned short* __restrict__ wo16,  // (256,256)
    const float* __restrict__ bo,
    float* __restrict__ y)                    // (b,256,n)
{
    const int id   = blockIdx.x;              // 0..511
    const int b    = (id & 7) * 2 + ((id >> 3) & 1);
    const int rest = id >> 4;                 // 0..31
    const int ct   = (rest & 3) * 64;
    const int pt   = (rest >> 2) * 128;
    const int t = threadIdx.x, wid = t >> 6, lane = t & 63;
    const int g = lane >> 4, ln = lane & 15;
    const int cb2 = ct + (wid & 1) * 32;
    const int pb  = pt + (wid >> 1) * 64;
    const unsigned short* ab = ao16 + (size_t)b * NTOK * CDIM;

    f32x4 acc[2][4];
    #pragma unroll
    for (int n = 0; n < 2; ++n)
        #pragma unroll
        for (int m = 0; m < 4; ++m) acc[n][m] = (f32x4){0.f, 0.f, 0.f, 0.f};

    #pragma unroll
    for (int kt = 0; kt < CDIM; kt += 32) {
        bf16x8 aw[2], bx[4];
        #pragma unroll
        for (int n = 0; n < 2; ++n)
            aw[n] = *(const bf16x8*)&wo16[(size_t)(cb2 + n * 16 + ln) * CDIM + kt + g * 8];
        #pragma unroll
        for (int m = 0; m < 4; ++m)
            bx[m] = *(const bf16x8*)&ab[(size_t)(pb + m * 16 + ln) * CDIM + kt + g * 8];
        #pragma unroll
        for (int n = 0; n < 2; ++n)
            #pragma unroll
            for (int m = 0; m < 4; ++m)
                acc[n][m] = __builtin_amdgcn_mfma_f32_16x16x32_bf16(aw[n], bx[m], acc[n][m], 0, 0, 0);
    }
    #pragma unroll
    for (int n = 0; n < 2; ++n)
        #pragma unroll
        for (int r = 0; r < 4; ++r) {
            const int c = cb2 + n * 16 + g * 4 + r;
            const float bias = bo[c];
            #pragma unroll
            for (int m = 0; m < 4; ++m)
                y[((size_t)b * CDIM + c) * NTOK + pb + m * 16 + ln] = acc[n][m][r] + bias;
        }
}

// ---------------------------------------------------------------------------
extern "C" void kernel_launch(void* const* d_in, const int* in_sizes, int n_in,
                              void* d_out, int out_size, void* d_ws, size_t ws_size,
                              hipStream_t stream) {
    const float* x        = (const float*)d_in[0];
    const float* Wq       = (const float*)d_in[1];
    const float* Wk       = (const float*)d_in[2];
    const float* Wv       = (const float*)d_in[3];
    const float* Wo       = (const float*)d_in[4];
    const float* bo       = (const float*)d_in[5];
    const float* rel_bias = (const float*)d_in[6];
    (void)in_sizes; (void)n_in; (void)ws_size; (void)out_size;
    // d_in[7] = rel_idx: unused — bias index computed analytically (j - p + 1056)

    unsigned short* ws16 = (unsigned short*)d_ws;
    unsigned short* w16  = ws16;                                   // 512 KB
    unsigned short* q16  = ws16 + 4 * 65536;                       // 8 MB
    unsigned short* k16  = q16 + (size_t)4 * 1024 * 1024;          // 8 MB
    unsigned short* v16  = k16 + (size_t)4 * 1024 * 1024;          // 8 MB
    unsigned short* ao16 = v16 + (size_t)4 * 1024 * 1024;          // 8 MB
    float* y = (float*)d_out;

    prepw_kernel<<<dim3(16, 4), 256, 0, stream>>>(Wq, Wk, Wv, Wo, w16);
    qkv_kernel<<<256, 1024, 0, stream>>>(x, w16, q16, k16, v16);
    attn_kernel<<<512, 1024, 0, stream>>>(q16, k16, v16, rel_bias, ao16);
    outproj_kernel<<<512, 256, 0, stream>>>(ao16, w16 + 3 * 65536, bo, y);
}

// Round 11
// 157.003 us; speedup vs baseline: 2.4567x; 2.4567x over previous
//
#include <hip/hip_runtime.h>

#define HEADS 8
#define HDIM 32
#define NTOK 1024
#define CDIM 256
#define BATCH 16
#define ATT_SCALE 0.17677669529663687f  // 32^-0.5
#define L2E 1.4426950408889634f
#define BSTR 1544   // bias copy stride (floats): 16B-aligned; 1544%32=8 -> ~2-way reads
#define XSTR 514    // qkv LDS x-tile row stride (f32): even (8B align) and 514%32=2
                    // -> column fragment reads land 2 lanes/bank = conflict-free

typedef __attribute__((ext_vector_type(8))) short bf16x8;   // 8 bf16, 4 VGPRs
typedef __attribute__((ext_vector_type(4))) float f32x4;    // MFMA C/D

__device__ __forceinline__ unsigned short f2bf(float f) {
    unsigned int u = __float_as_uint(f);
    return (unsigned short)((u + 0x7fffu + ((u >> 16) & 1u)) >> 16);  // RNE
}

// pack two f32 -> (bf16(lo) | bf16(hi)<<16) in one instruction; RNE == f2bf
__device__ __forceinline__ unsigned cvt_pk_bf16(float lo, float hi) {
    unsigned r;
    asm("v_cvt_pk_bf16_f32 %0, %1, %2" : "=v"(r) : "v"(lo), "v"(hi));
    return r;
}

// ---------------------------------------------------------------------------
// Weight prep only: fp32 -> bf16, Wk pre-scaled by ATT_SCALE*log2(e).
// ---------------------------------------------------------------------------
__global__ __launch_bounds__(256) void prepw_kernel(
    const float* __restrict__ Wq, const float* __restrict__ Wk,
    const float* __restrict__ Wv, const float* __restrict__ Wo,
    unsigned short* __restrict__ w16)
{
    const int t = threadIdx.x;
    const int which = blockIdx.y;
    const float* src = (which == 0) ? Wq : ((which == 1) ? Wk : ((which == 2) ? Wv : Wo));
    const float scale = (which == 1) ? (ATT_SCALE * L2E) : 1.0f;
    const int base = (blockIdx.x * 256 + t) * 16;
    #pragma unroll
    for (int i = 0; i < 4; ++i) {
        const int idx = base + i * 4;
        float4 v = *(const float4*)&src[idx];
        union { unsigned short h[4]; uint2 u; } pk;
        pk.h[0] = f2bf(v.x * scale); pk.h[1] = f2bf(v.y * scale);
        pk.h[2] = f2bf(v.z * scale); pk.h[3] = f2bf(v.w * scale);
        *(uint2*)&w16[(size_t)which * 65536 + idx] = pk.u;
    }
}

// ---------------------------------------------------------------------------
// QKV GEMM with INTEGRATED x transpose.  Block = (b,h,token-half), 16 waves.
// Per 32-c chunk: stage x[kt..kt+32)[512 tokens] f32 -> LDS (lane-contiguous
// float2 writes, conflict-free), barrier, column-read 8 c per fragment
// (stride XSTR=514: 2 lanes/bank = free), cvt_pk -> bf16 (RNE == f2bf),
// 12 MFMA sharing x fragments.  K/V written fragment-major (attn's LDS
// layout); Q row-major.  (R7 configuration -- best measured total.)
// ---------------------------------------------------------------------------
__global__ __launch_bounds__(1024, 4) void qkv_kernel(
    const float* __restrict__ x,              // (b,c,n) f32
    const unsigned short* __restrict__ w16,   // wq|wk|wv|wo (wk pre-scaled)
    unsigned short* __restrict__ q16,         // (b,n,h,32)
    unsigned short* __restrict__ k16,         // (b,h, 64 frag, 512)
    unsigned short* __restrict__ v16)         // (b,h, 64 frag, 512)
{
    __shared__ __align__(16) float lx[32 * XSTR];   // 64.25 KB

    const int id   = blockIdx.x;                    // 0..255
    const int bh_i = (id & 7) * 16 + (id >> 4);
    const int tokhalf = (id >> 3) & 1;
    const int b = bh_i >> 3, h = bh_i & 7;

    const int t = threadIdx.x, wid = t >> 6, lane = t & 63;
    const int g = lane >> 4, ln = lane & 15;
    const int trl = wid * 32;                       // wave's 32 tokens (block-local)
    const int tok0 = tokhalf * 512;

    const float* xb = x + (size_t)b * CDIM * NTOK;
    const unsigned short* wqh = w16 + (size_t)(h * 32) * CDIM;
    const unsigned short* wkh = w16 + 65536 + (size_t)(h * 32) * CDIM;
    const unsigned short* wvh = w16 + 2 * 65536 + (size_t)(h * 32) * CDIM;

    f32x4 aq[2][2], ak[2][2], av[2][2];
    #pragma unroll
    for (int m = 0; m < 2; ++m)
        #pragma unroll
        for (int n = 0; n < 2; ++n) {
            aq[m][n] = (f32x4){0.f, 0.f, 0.f, 0.f};
            ak[m][n] = (f32x4){0.f, 0.f, 0.f, 0.f};
            av[n][m] = (f32x4){0.f, 0.f, 0.f, 0.f};
        }

    const int scc = t >> 7;          // staging c-row within octet (0..7)
    const int sn0 = (t & 127) * 4;   // staging token offset (one float4)

    for (int kt = 0; kt < CDIM; kt += 32) {
        if (kt) __syncthreads();     // prior chunk's reads done before overwrite
        // ---- stage: 32 c-rows x 512 tokens, f32 (coalesced 2KB per 128 thr) ----
        #pragma unroll
        for (int p = 0; p < 4; ++p) {
            const int cc = scc + 8 * p;
            const float4 v = *(const float4*)&xb[(size_t)(kt + cc) * NTOK + tok0 + sn0];
            *(float2*)&lx[cc * XSTR + sn0]     = make_float2(v.x, v.y);
            *(float2*)&lx[cc * XSTR + sn0 + 2] = make_float2(v.z, v.w);
        }
        __syncthreads();
        // ---- fragments: column reads (8 c per token), cvt_pk -> bf16 ----
        bf16x8 xf[2];
        #pragma unroll
        for (int m = 0; m < 2; ++m) {
            const float* col = &lx[(size_t)(g * 8) * XSTR + trl + m * 16 + ln];
            union { unsigned u4[4]; bf16x8 v; } pk;
            #pragma unroll
            for (int p = 0; p < 4; ++p)
                pk.u4[p] = cvt_pk_bf16(col[(2 * p) * XSTR], col[(2 * p + 1) * XSTR]);
            xf[m] = pk.v;
        }
        bf16x8 wqf[2], wkf[2], wvf[2];
        #pragma unroll
        for (int n = 0; n < 2; ++n) {
            wqf[n] = *(const bf16x8*)&wqh[(size_t)(n * 16 + ln) * CDIM + kt + g * 8];
            wkf[n] = *(const bf16x8*)&wkh[(size_t)(n * 16 + ln) * CDIM + kt + g * 8];
            wvf[n] = *(const bf16x8*)&wvh[(size_t)(n * 16 + ln) * CDIM + kt + g * 8];
        }
        #pragma unroll
        for (int m = 0; m < 2; ++m)
            #pragma unroll
            for (int n = 0; n < 2; ++n) {
                aq[m][n] = __builtin_amdgcn_mfma_f32_16x16x32_bf16(xf[m], wqf[n], aq[m][n], 0, 0, 0);
                ak[m][n] = __builtin_amdgcn_mfma_f32_16x16x32_bf16(xf[m], wkf[n], ak[m][n], 0, 0, 0);
                av[n][m] = __builtin_amdgcn_mfma_f32_16x16x32_bf16(wvf[n], xf[m], av[n][m], 0, 0, 0);
            }
    }

    const int tr = tok0 + trl;
    // Q store, row-major (b,n,h,32).  aq[m][n][r] = Q[row=tr+m*16+g*4+r][col=n*16+ln].
    #pragma unroll
    for (int m = 0; m < 2; ++m)
        #pragma unroll
        for (int n = 0; n < 2; ++n)
            #pragma unroll
            for (int r = 0; r < 4; ++r)
                q16[((size_t)(b * NTOK + tr + m * 16 + g * 4 + r) * 8 + h) * 32 + n * 16 + ln] =
                    f2bf(aq[m][n][r]);

    // K store, fragment-major.
    unsigned short* kb16 = k16 + (size_t)(b * 8 + h) * 32768;
    const int fK = (tokhalf * 16 + wid) * 2 + (g & 1);
    #pragma unroll
    for (int m = 0; m < 2; ++m)
        #pragma unroll
        for (int n = 0; n < 2; ++n) {
            const int lhi = (2 * n + (ln >> 3)) * 16 + (m * 2 + (g >> 1)) * 4;
            #pragma unroll
            for (int r = 0; r < 4; ++r)
                kb16[fK * 512 + (lhi + r) * 8 + (ln & 7)] = f2bf(ak[m][n][r]);
        }

    // V store, fragment-major.  av[n][m][r] = V[d=n*16+g*4+r][tok=tr+m*16+ln].
    unsigned short* vb16 = v16 + (size_t)(b * 8 + h) * 32768;
    #pragma unroll
    for (int n = 0; n < 2; ++n) {
        const int fV = (tokhalf * 16 + wid) * 2 + n;
        #pragma unroll
        for (int m = 0; m < 2; ++m) {
            const int lnb = (m * 2 + (ln >> 3)) * 16 + g * 4;
            #pragma unroll
            for (int r = 0; r < 4; ++r)
                vb16[fV * 512 + (lnb + r) * 8 + (ln & 7)] = f2bf(av[n][m][r]);
        }
    }
}

// ---------------------------------------------------------------------------
// Flash attention.  Block = (b, h, query-half): 1024 thr/16 waves.
// Proven R6/R7 schedule: K/V staged global->reg->LDS (linear, conflict-free),
// bias4 LDS table, one barrier, then the R1 stage-2 loop (K+bias prefetched
// 1 iter ahead, cvt_pk packing, setprio on MFMA clusters).
// Structural note: 152.6 KB LDS pins 1 block/CU (4 waves/SIMD).  2 blocks/CU
// needs <=80 KB (K/V alone is 128 KB) AND <=64 VGPR (loop needs ~100) --
// both infeasible (R10: forced 8 waves/SIMD -> 776 MB scratch spill).
// ---------------------------------------------------------------------------
__global__ __launch_bounds__(1024, 4) void attn_kernel(
    const unsigned short* __restrict__ q16,   // (b,n,h,32)
    const unsigned short* __restrict__ k16,   // (b,h,64,512) frag-major
    const unsigned short* __restrict__ v16,   // (b,h,64,512) frag-major
    const float* __restrict__ rel_bias,       // (h, 3969)
    unsigned short* __restrict__ ao16)        // (b, n, 256)
{
    __shared__ __align__(16) unsigned char smem[65536 + 65536 + BSTR * 4 * 4];
    unsigned short* k_s   = (unsigned short*)smem;             // 64 frags x 512 shorts
    unsigned short* v_s   = (unsigned short*)(smem + 65536);   // 64 frags x 512 shorts
    float*          bias4 = (float*)(smem + 131072);           // [4][BSTR]

    const int id   = blockIdx.x;                    // 0..255
    const int bh_i = (id & 7) * 16 + (id >> 4);     // XCD x owns bh [16x,16x+16)
    const int half = (id >> 3) & 1;
    const int b = bh_i >> 3, h = bh_i & 7;

    const int t = threadIdx.x, wid = t >> 6, lane = t & 63;
    const int g = lane >> 4, ln = lane & 15;
    const int qb = half * 512 + wid * 32;           // wave's 32 queries

    const unsigned short* kbh = k16 + (size_t)(b * 8 + h) * 32768;
    const unsigned short* vbh = v16 + (size_t)(b * 8 + h) * 32768;

    // ---- stage K/V fragments: global -> reg (issue early) ----
    bf16x8 sk[4], sv[4];
    #pragma unroll
    for (int j = 0; j < 4; ++j) {
        const int f = wid * 4 + j;
        sk[j] = *(const bf16x8*)&kbh[(size_t)f * 512 + lane * 8];
        sv[j] = *(const bf16x8*)&vbh[(size_t)f * 512 + lane * 8];
    }
    // ---- Q fragments ----
    const bf16x8 aq0 = *(const bf16x8*)&q16[((size_t)(b * NTOK + qb + ln) * 8 + h) * 32 + g * 8];
    const bf16x8 aq1 = *(const bf16x8*)&q16[((size_t)(b * NTOK + qb + 16 + ln) * 8 + h) * 32 + g * 8];

    // ---- bias*log2e -> 4 shift-aligned copies (overlaps the loads above) ----
    {
        const int START = 544 - 512 * half;         // 4-aligned window base
        const float* brow = rel_bias + (size_t)h * 3969;
        for (int i = t; i < 1540; i += 1024) {
            #pragma unroll
            for (int a = 0; a < 4; ++a)
                bias4[a * BSTR + i] = brow[START + a + i] * L2E;
        }
    }

    // ---- commit staged frags to LDS (linear in lane = conflict-free) ----
    #pragma unroll
    for (int j = 0; j < 4; ++j) {
        const int f = wid * 4 + j;
        *(bf16x8*)&k_s[(size_t)f * 512 + lane * 8] = sk[j];
        *(bf16x8*)&v_s[(size_t)f * 512 + lane * 8] = sv[j];
    }

    __syncthreads();   // K, V, bias all LDS-resident

    // ---- Stage 2: attention main loop (R1 schedule, verbatim) ----
    const int boffL = 512 + 8 * g - wid * 32 - ln;   // local bias offset
    const int ba = boffL & 3;
    const float* bb = &bias4[ba * BSTR + (boffL - ba)];
    const unsigned short* kfp = k_s + lane * 8;      // frag stride 512 shorts
    const unsigned short* vfp = v_s + lane * 8;

    f32x4 o00 = {0.f,0.f,0.f,0.f}, o01 = {0.f,0.f,0.f,0.f};
    f32x4 o10 = {0.f,0.f,0.f,0.f}, o11 = {0.f,0.f,0.f,0.f};
    f32x4 ls0 = {0.f,0.f,0.f,0.f}, ls1 = {0.f,0.f,0.f,0.f};
    const short one_bf = (short)0x3F80;
    const bf16x8 ones = {one_bf,one_bf,one_bf,one_bf,one_bf,one_bf,one_bf,one_bf};

    // prologue: iter-0 K fragments + bias C-operands
    bf16x8 kf0 = *(const bf16x8*)&kfp[0];
    bf16x8 kf1 = *(const bf16x8*)&kfp[512];
    f32x4  cA0 = *(const f32x4*)&bb[0];
    f32x4  cA1 = *(const f32x4*)&bb[4];
    f32x4  cB0 = *(const f32x4*)&bb[-16];
    f32x4  cB1 = *(const f32x4*)&bb[-12];

    for (int kb = 0; kb < NTOK; kb += 32) {
        const int fi = (kb >> 5) * 2;
        // V for THIS iter: consumed only after S-MFMA + exp chain -> self-hiding.
        const bf16x8 vA0 = *(const bf16x8*)&vfp[fi * 512];
        const bf16x8 vA1 = *(const bf16x8*)&vfp[(fi + 1) * 512];
        // prefetch NEXT iter's K + bias (wrap keeps addresses in-bounds).
        const int kn = (kb + 32) & (NTOK - 1);
        const int fn = (kn >> 5) * 2;
        const bf16x8 nk0 = *(const bf16x8*)&kfp[fn * 512];
        const bf16x8 nk1 = *(const bf16x8*)&kfp[(fn + 1) * 512];
        const f32x4  nA0 = *(const f32x4*)&bb[kn];
        const f32x4  nA1 = *(const f32x4*)&bb[kn + 4];
        const f32x4  nB0 = *(const f32x4*)&bb[kn - 16];
        const f32x4  nB1 = *(const f32x4*)&bb[kn - 12];

        __builtin_amdgcn_s_setprio(1);
        f32x4 s00 = __builtin_amdgcn_mfma_f32_16x16x32_bf16(kf0, aq0, cA0, 0, 0, 0);
        f32x4 s01 = __builtin_amdgcn_mfma_f32_16x16x32_bf16(kf1, aq0, cA1, 0, 0, 0);
        f32x4 s10 = __builtin_amdgcn_mfma_f32_16x16x32_bf16(kf0, aq1, cB0, 0, 0, 0);
        f32x4 s11 = __builtin_amdgcn_mfma_f32_16x16x32_bf16(kf1, aq1, cB1, 0, 0, 0);
        __builtin_amdgcn_s_setprio(0);

        // Pack P: shorts [e(s0[0..3]) | e(s1[0..3])] = keys kb+8g+0..7 in order.
        union { unsigned u4[4]; bf16x8 v; } ap0, ap1;
        ap0.u4[0] = cvt_pk_bf16(__builtin_amdgcn_exp2f(s00[0]), __builtin_amdgcn_exp2f(s00[1]));
        ap0.u4[1] = cvt_pk_bf16(__builtin_amdgcn_exp2f(s00[2]), __builtin_amdgcn_exp2f(s00[3]));
        ap0.u4[2] = cvt_pk_bf16(__builtin_amdgcn_exp2f(s01[0]), __builtin_amdgcn_exp2f(s01[1]));
        ap0.u4[3] = cvt_pk_bf16(__builtin_amdgcn_exp2f(s01[2]), __builtin_amdgcn_exp2f(s01[3]));
        ap1.u4[0] = cvt_pk_bf16(__builtin_amdgcn_exp2f(s10[0]), __builtin_amdgcn_exp2f(s10[1]));
        ap1.u4[1] = cvt_pk_bf16(__builtin_amdgcn_exp2f(s10[2]), __builtin_amdgcn_exp2f(s10[3]));
        ap1.u4[2] = cvt_pk_bf16(__builtin_amdgcn_exp2f(s11[0]), __builtin_amdgcn_exp2f(s11[1]));
        ap1.u4[3] = cvt_pk_bf16(__builtin_amdgcn_exp2f(s11[2]), __builtin_amdgcn_exp2f(s11[3]));

        __builtin_amdgcn_s_setprio(1);
        o00 = __builtin_amdgcn_mfma_f32_16x16x32_bf16(ap0.v, vA0, o00, 0, 0, 0);
        o01 = __builtin_amdgcn_mfma_f32_16x16x32_bf16(ap0.v, vA1, o01, 0, 0, 0);
        ls0 = __builtin_amdgcn_mfma_f32_16x16x32_bf16(ap0.v, ones, ls0, 0, 0, 0);
        o10 = __builtin_amdgcn_mfma_f32_16x16x32_bf16(ap1.v, vA0, o10, 0, 0, 0);
        o11 = __builtin_amdgcn_mfma_f32_16x16x32_bf16(ap1.v, vA1, o11, 0, 0, 0);
        ls1 = __builtin_amdgcn_mfma_f32_16x16x32_bf16(ap1.v, ones, ls1, 0, 0, 0);
        __builtin_amdgcn_s_setprio(0);

        kf0 = nk0; kf1 = nk1;
        cA0 = nA0; cA1 = nA1; cB0 = nB0; cB1 = nB1;
    }

    #pragma unroll
    for (int r = 0; r < 4; ++r) {
        float i0 = 1.f / ls0[r], i1 = 1.f / ls1[r];
        o00[r] *= i0; o01[r] *= i0;
        o10[r] *= i1; o11[r] *= i1;
    }

    __syncthreads();   // all waves done with k_s; overlay otr on K region
    unsigned short (*otr)[32][40] = (unsigned short(*)[32][40])smem;
    #pragma unroll
    for (int r = 0; r < 4; ++r) {
        otr[wid][g * 4 + r][ln]           = f2bf(o00[r]);
        otr[wid][g * 4 + r][16 + ln]      = f2bf(o01[r]);
        otr[wid][16 + g * 4 + r][ln]      = f2bf(o10[r]);
        otr[wid][16 + g * 4 + r][16 + ln] = f2bf(o11[r]);
    }
    // same-wave region: DS in-order, no barrier.  2 lanes/row x 16 d each.
    const int row = lane >> 1;
    const int ch  = (lane & 1) * 16;
    uint4 st0 = *(uint4*)&otr[wid][row][ch];
    uint4 st1 = *(uint4*)&otr[wid][row][ch + 8];
    unsigned short* dst = &ao16[((size_t)b * NTOK + qb + row) * CDIM + h * HDIM + ch];
    *(uint4*)dst     = st0;
    *(uint4*)&dst[8] = st1;
}

// ---------------------------------------------------------------------------
// Output projection: 64c x 128p per block, wave = 2 c-frags x 4 p-frags.
// XCD-swizzled flat grid 512.
// ---------------------------------------------------------------------------
__global__ __launch_bounds__(256) void outproj_kernel(
    const unsigned short* __restrict__ ao16,  // (b,n,256)
    const unsigned short* __restrict__ wo16,  // (256,256)
    const float* __restrict__ bo,
    float* __restrict__ y)                    // (b,256,n)
{
    const int id   = blockIdx.x;              // 0..511
    const int b    = (id & 7) * 2 + ((id >> 3) & 1);
    const int rest = id >> 4;                 // 0..31
    const int ct   = (rest & 3) * 64;
    const int pt   = (rest >> 2) * 128;
    const int t = threadIdx.x, wid = t >> 6, lane = t & 63;
    const int g = lane >> 4, ln = lane & 15;
    const int cb2 = ct + (wid & 1) * 32;
    const int pb  = pt + (wid >> 1) * 64;
    const unsigned short* ab = ao16 + (size_t)b * NTOK * CDIM;

    f32x4 acc[2][4];
    #pragma unroll
    for (int n = 0; n < 2; ++n)
        #pragma unroll
        for (int m = 0; m < 4; ++m) acc[n][m] = (f32x4){0.f, 0.f, 0.f, 0.f};

    #pragma unroll
    for (int kt = 0; kt < CDIM; kt += 32) {
        bf16x8 aw[2], bx[4];
        #pragma unroll
        for (int n = 0; n < 2; ++n)
            aw[n] = *(const bf16x8*)&wo16[(size_t)(cb2 + n * 16 + ln) * CDIM + kt + g * 8];
        #pragma unroll
        for (int m = 0; m < 4; ++m)
            bx[m] = *(const bf16x8*)&ab[(size_t)(pb + m * 16 + ln) * CDIM + kt + g * 8];
        #pragma unroll
        for (int n = 0; n < 2; ++n)
            #pragma unroll
            for (int m = 0; m < 4; ++m)
                acc[n][m] = __builtin_amdgcn_mfma_f32_16x16x32_bf16(aw[n], bx[m], acc[n][m], 0, 0, 0);
    }
    #pragma unroll
    for (int n = 0; n < 2; ++n)
        #pragma unroll
        for (int r = 0; r < 4; ++r) {
            const int c = cb2 + n * 16 + g * 4 + r;
            const float bias = bo[c];
            #pragma unroll
            for (int m = 0; m < 4; ++m)
                y[((size_t)b * CDIM + c) * NTOK + pb + m * 16 + ln] = acc[n][m][r] + bias;
        }
}

// ---------------------------------------------------------------------------
extern "C" void kernel_launch(void* const* d_in, const int* in_sizes, int n_in,
                              void* d_out, int out_size, void* d_ws, size_t ws_size,
                              hipStream_t stream) {
    const float* x        = (const float*)d_in[0];
    const float* Wq       = (const float*)d_in[1];
    const float* Wk       = (const float*)d_in[2];
    const float* Wv       = (const float*)d_in[3];
    const float* Wo       = (const float*)d_in[4];
    const float* bo       = (const float*)d_in[5];
    const float* rel_bias = (const float*)d_in[6];
    (void)in_sizes; (void)n_in; (void)ws_size; (void)out_size;
    // d_in[7] = rel_idx: unused — bias index computed analytically (j - p + 1056)

    unsigned short* ws16 = (unsigned short*)d_ws;
    unsigned short* w16  = ws16;                                   // 512 KB
    unsigned short* q16  = ws16 + 4 * 65536;                       // 8 MB
    unsigned short* k16  = q16 + (size_t)4 * 1024 * 1024;          // 8 MB
    unsigned short* v16  = k16 + (size_t)4 * 1024 * 1024;          // 8 MB
    unsigned short* ao16 = v16 + (size_t)4 * 1024 * 1024;          // 8 MB
    float* y = (float*)d_out;

    prepw_kernel<<<dim3(16, 4), 256, 0, stream>>>(Wq, Wk, Wv, Wo, w16);
    qkv_kernel<<<256, 1024, 0, stream>>>(x, w16, q16, k16, v16);
    attn_kernel<<<256, 1024, 0, stream>>>(q16, k16, v16, rel_bias, ao16);
    outproj_kernel<<<512, 256, 0, stream>>>(ao16, w16 + 3 * 65536, bo, y);
}